// Round 4
// baseline (663.600 us; speedup 1.0000x reference)
//
#include <hip/hip_runtime.h>

#define HH 256
#define WW 256
#define HW (HH * WW)

// prep: E[i,m,l] = exp(w[i,m,l]) -> ws[0..119]
__global__ void prep_kernel(const float* __restrict__ w, float* __restrict__ E) {
    int t = threadIdx.x;
    if (t < 120) E[t] = expf(w[t]);
}

__device__ __forceinline__ float sgnf(float d) {
    return (d > 0.0f) ? 1.0f : ((d < 0.0f) ? -1.0f : 0.0f);
}

// Kernel A: compute t[n][m][h][w] (5 planes per image, borders zeroed) into ws,
// and write the 3 center-copy output channels. Grid: 32 x 64 row-quads, 256 thr.
__global__ __launch_bounds__(256) void lbp_a(
    const float* __restrict__ x,    // (32,3,256,256)
    const float* __restrict__ E,    // exp(w) [120]
    float* __restrict__ t,          // (32,5,256,256) workspace
    float* __restrict__ out)        // (32,67,256,256)
{
    const int tid  = threadIdx.x;
    const int bid  = blockIdx.x;
    const int n    = bid >> 6;
    const int q    = bid & 63;
    const int wv   = tid >> 6;
    const int lane = tid & 63;
    const int r    = q * 4 + wv;
    const int cb   = lane * 4;

    float* ob = out + (size_t)n * 67 * HW + (size_t)r * WW + cb;
    float* tb = t   + (size_t)n * 5  * HW + (size_t)r * WW + cb;

    if (r == 0 || r == HH - 1) {
        const float4 z = {0.f, 0.f, 0.f, 0.f};
        #pragma unroll
        for (int ch = 0; ch < 3; ++ch) *(float4*)(ob + (size_t)ch * HW) = z;
        #pragma unroll
        for (int m = 0; m < 5; ++m)  *(float4*)(tb + (size_t)m * HW) = z;
        return;
    }

    const int cl = (cb == 0) ? 0 : cb - 1;
    const int cr = (cb + 4 > WW - 1) ? WW - 1 : cb + 4;
    const float* xb = x + (size_t)n * 3 * HW + (size_t)r * WW;

    float tacc[5][4];
    #pragma unroll
    for (int m = 0; m < 5; ++m)
        #pragma unroll
        for (int j = 0; j < 4; ++j) tacc[m][j] = 0.f;

    #pragma unroll
    for (int i = 0; i < 3; ++i) {
        const float* xr = xb + (size_t)i * HW;
        float4 m4 = *(const float4*)(xr - WW + cb);
        float4 c4 = *(const float4*)(xr + cb);
        float4 p4 = *(const float4*)(xr + WW + cb);

        float rm[6], rc[6], rp[6];
        rm[0] = xr[-WW + cl]; rm[1] = m4.x; rm[2] = m4.y; rm[3] = m4.z; rm[4] = m4.w; rm[5] = xr[-WW + cr];
        rc[0] = xr[cl];       rc[1] = c4.x; rc[2] = c4.y; rc[3] = c4.z; rc[4] = c4.w; rc[5] = xr[cr];
        rp[0] = xr[ WW + cl]; rp[1] = p4.x; rp[2] = p4.y; rp[3] = p4.z; rp[4] = p4.w; rp[5] = xr[ WW + cr];

        float cv[4];
        #pragma unroll
        for (int j = 0; j < 4; ++j) {
            const float ctr = rc[j + 1];
            cv[j] = ctr;
            float s0 = sgnf(ctr - rm[j]);
            float s1 = sgnf(ctr - rm[j + 1]);
            float s2 = sgnf(ctr - rm[j + 2]);
            float s3 = sgnf(ctr - rc[j]);
            float s4 = sgnf(ctr - rp[j]);
            float s5 = sgnf(ctr - rp[j + 1]);
            float s6 = sgnf(ctr - rp[j + 2]);
            float s7 = sgnf(ctr - rc[j + 2]);

            #pragma unroll
            for (int m = 0; m < 5; ++m) {
                const float* Em = E + i * 40 + m * 8;   // wave-uniform -> s_load
                float a = tacc[m][j];
                a = fmaf(s0, Em[0], a);
                a = fmaf(s1, Em[1], a);
                a = fmaf(s2, Em[2], a);
                a = fmaf(s3, Em[3], a);
                a = fmaf(s4, Em[4], a);
                a = fmaf(s5, Em[5], a);
                a = fmaf(s6, Em[6], a);
                a = fmaf(s7, Em[7], a);
                tacc[m][j] = a;
            }
        }

        float4 cc;
        cc.x = (cb != 0) ? cv[0] : 0.f;
        cc.y = cv[1];
        cc.z = cv[2];
        cc.w = (cb + 3 != WW - 1) ? cv[3] : 0.f;
        *(float4*)(ob + (size_t)i * HW) = cc;
    }

    // zero border columns so y-channels become exactly 0 there
    #pragma unroll
    for (int j = 0; j < 4; ++j) {
        const int col = cb + j;
        if (col == 0 || col == WW - 1) {
            #pragma unroll
            for (int m = 0; m < 5; ++m) tacc[m][j] = 0.f;
        }
    }

    #pragma unroll
    for (int m = 0; m < 5; ++m) {
        float4 tv = {tacc[m][0], tacc[m][1], tacc[m][2], tacc[m][3]};
        *(float4*)(tb + (size_t)m * HW) = tv;
    }
}

// Kernel B: y[n][o][h][w] = sum_m t[n][m][h][w] * wl[m][o], written as linear
// plane streams. Grid: 512 blocks = 32 n x 16 channel-quads; 512 threads.
// LDS stages 16 rows of all 5 t-planes (80 KB); each wave-pair owns one channel.
__global__ __launch_bounds__(512) void lbp_b(
    const float* __restrict__ t,    // (32,5,256,256)
    const float* __restrict__ wl,   // (5,64)
    float* __restrict__ out)        // (32,67,256,256)
{
    __shared__ float tl[5 * 16 * 256];   // 80 KB

    const int tid  = threadIdx.x;
    const int bid  = blockIdx.x;
    const int n    = bid & 31;           // bid%8 == n%8 -> same-n blocks share an XCD
    const int og   = bid >> 5;           // 0..15, 4 channels each
    const int wv   = tid >> 6;
    const int lane = tid & 63;
    const int ch   = og * 4 + (wv >> 1); // y-channel 0..63
    const int rh   = wv & 1;             // row half within tile

    const float* tn = t + (size_t)n * 5 * HW;
    float* ob = out + (size_t)n * 67 * HW + (size_t)(3 + ch) * HW + (size_t)lane * 4;

    const float w0 = wl[0 * 64 + ch];
    const float w1 = wl[1 * 64 + ch];
    const float w2 = wl[2 * 64 + ch];
    const float w3 = wl[3 * 64 + ch];
    const float w4 = wl[4 * 64 + ch];

    for (int rb = 0; rb < HH; rb += 16) {
        // stage 5 x 16 x 256 floats; thread copies 10 float4s, linear per wave
        #pragma unroll
        for (int k = 0; k < 10; ++k) {
            const int f = (k * 512 + tid) * 4;       // flat float idx, 0..20479
            const int m = f >> 12;                   // 4096 floats per m-tile
            const int within = f & 4095;
            float4 v = *(const float4*)(tn + (size_t)m * HW + (size_t)rb * WW + within);
            *(float4*)(&tl[f]) = v;
        }
        __syncthreads();

        #pragma unroll
        for (int rr8 = 0; rr8 < 8; ++rr8) {
            const int rr = rh * 8 + rr8;
            const int base = rr * 256 + lane * 4;
            float4 t0 = *(const float4*)(&tl[0 * 4096 + base]);
            float4 t1 = *(const float4*)(&tl[1 * 4096 + base]);
            float4 t2 = *(const float4*)(&tl[2 * 4096 + base]);
            float4 t3 = *(const float4*)(&tl[3 * 4096 + base]);
            float4 t4 = *(const float4*)(&tl[4 * 4096 + base]);
            float4 y;
            y.x = fmaf(t4.x, w4, fmaf(t3.x, w3, fmaf(t2.x, w2, fmaf(t1.x, w1, t0.x * w0))));
            y.y = fmaf(t4.y, w4, fmaf(t3.y, w3, fmaf(t2.y, w2, fmaf(t1.y, w1, t0.y * w0))));
            y.z = fmaf(t4.z, w4, fmaf(t3.z, w3, fmaf(t2.z, w2, fmaf(t1.z, w1, t0.z * w0))));
            y.w = fmaf(t4.w, w4, fmaf(t3.w, w3, fmaf(t2.w, w2, fmaf(t1.w, w1, t0.w * w0))));
            *(float4*)(ob + (size_t)(rb + rr) * WW) = y;
        }
        __syncthreads();
    }
}

extern "C" void kernel_launch(void* const* d_in, const int* in_sizes, int n_in,
                              void* d_out, int out_size, void* d_ws, size_t ws_size,
                              hipStream_t stream) {
    const float* x  = (const float*)d_in[0];
    const float* w  = (const float*)d_in[1];
    const float* wl = (const float*)d_in[2];
    float* out = (float*)d_out;
    float* E   = (float*)d_ws;              // 120 floats
    float* t   = (float*)d_ws + 256;        // 32*5*65536 floats = 41.9 MB

    prep_kernel<<<1, 128, 0, stream>>>(w, E);
    lbp_a<<<32 * 64, 256, 0, stream>>>(x, E, t, out);
    lbp_b<<<512, 512, 0, stream>>>(t, wl, out);
}

// Round 9
// 570.046 us; speedup vs baseline: 1.1641x; 1.1641x over previous
//
#include <hip/hip_runtime.h>

#define HH 256
#define WW 256
#define HW (HH * WW)

typedef float f4v __attribute__((ext_vector_type(4)));

__device__ __forceinline__ void nt_store4(float* p, float a, float b, float c, float d) {
    f4v v = {a, b, c, d};
    __builtin_nontemporal_store(v, (f4v*)p);
}

// Prep: E[i,m,l] = exp(w[i,m,l]) (120 floats) at ws[0..119];
//       wlT[o,m] = wl[m,o]       (320 floats) at ws[128..447].
__global__ void prep_kernel(const float* __restrict__ w, const float* __restrict__ wl,
                            float* __restrict__ ws) {
    int t = threadIdx.x;
    if (t < 120) ws[t] = expf(w[t]);
    if (t >= 128 && t < 128 + 320) {
        int idx = t - 128;          // idx = o*5 + m
        int o = idx / 5, m = idx - o * 5;
        ws[t] = wl[m * 64 + o];
    }
}

__device__ __forceinline__ float sgnf(float d) {
    return (d > 0.0f) ? 1.0f : ((d < 0.0f) ? -1.0f : 0.0f);
}

// Grid: 32 images x 64 row-quads, 256 threads.
// Wave w (0..3) owns row q*4+w; lane owns a 4-column quad. All stores are
// non-temporal dwordx4 (output is write-once, keep it out of L2).
__global__ __launch_bounds__(256) void lbp_kernel(
    const float* __restrict__ x,    // (32,3,256,256)
    const float* __restrict__ ws,   // E[120] @0, wlT[320] @128
    float* __restrict__ out)        // (32,67,256,256)
{
    const int tid  = threadIdx.x;
    const int bid  = blockIdx.x;
    const int n    = bid >> 6;
    const int q    = bid & 63;
    const int wv   = tid >> 6;
    const int lane = tid & 63;
    const int r    = q * 4 + wv;
    const int cb   = lane * 4;

    float* ob = out + (size_t)n * 67 * HW + (size_t)r * WW + cb;

    // Rows 0 / 255: wave-uniform zero fill (output is poisoned 0xAA).
    if (r == 0 || r == HH - 1) {
        #pragma unroll
        for (int ch = 0; ch < 67; ++ch)
            nt_store4(ob + (size_t)ch * HW, 0.f, 0.f, 0.f, 0.f);
        return;
    }

    // Clamped scalar-neighbor columns (keeps all loads in-bounds; border
    // pixels' results are zeroed below).
    const int cl = (cb == 0) ? 0 : cb - 1;
    const int cr = (cb + 4 > WW - 1) ? WW - 1 : cb + 4;

    const float* xb = x + (size_t)n * 3 * HW + (size_t)r * WW;

    float tacc[5][4];
    #pragma unroll
    for (int m = 0; m < 5; ++m)
        #pragma unroll
        for (int j = 0; j < 4; ++j) tacc[m][j] = 0.f;

    #pragma unroll
    for (int i = 0; i < 3; ++i) {
        const float* xr = xb + (size_t)i * HW;

        float4 m4 = *(const float4*)(xr - WW + cb);
        float4 c4 = *(const float4*)(xr + cb);
        float4 p4 = *(const float4*)(xr + WW + cb);

        float rm[6], rc[6], rp[6];
        rm[0] = xr[-WW + cl]; rm[1] = m4.x; rm[2] = m4.y; rm[3] = m4.z; rm[4] = m4.w; rm[5] = xr[-WW + cr];
        rc[0] = xr[cl];       rc[1] = c4.x; rc[2] = c4.y; rc[3] = c4.z; rc[4] = c4.w; rc[5] = xr[cr];
        rp[0] = xr[ WW + cl]; rp[1] = p4.x; rp[2] = p4.y; rp[3] = p4.z; rp[4] = p4.w; rp[5] = xr[ WW + cr];

        float cv[4];
        #pragma unroll
        for (int j = 0; j < 4; ++j) {
            const float ctr = rc[j + 1];
            cv[j] = ctr;
            // _OFFSETS order: (-1,-1),(-1,0),(-1,+1),(0,-1),(+1,-1),(+1,0),(+1,+1),(0,+1)
            float s0 = sgnf(ctr - rm[j]);
            float s1 = sgnf(ctr - rm[j + 1]);
            float s2 = sgnf(ctr - rm[j + 2]);
            float s3 = sgnf(ctr - rc[j]);
            float s4 = sgnf(ctr - rp[j]);
            float s5 = sgnf(ctr - rp[j + 1]);
            float s6 = sgnf(ctr - rp[j + 2]);
            float s7 = sgnf(ctr - rc[j + 2]);

            #pragma unroll
            for (int m = 0; m < 5; ++m) {
                const float* Em = ws + i * 40 + m * 8;  // wave-uniform -> scalar loads
                float a = tacc[m][j];
                a = fmaf(s0, Em[0], a);
                a = fmaf(s1, Em[1], a);
                a = fmaf(s2, Em[2], a);
                a = fmaf(s3, Em[3], a);
                a = fmaf(s4, Em[4], a);
                a = fmaf(s5, Em[5], a);
                a = fmaf(s6, Em[6], a);
                a = fmaf(s7, Em[7], a);
                tacc[m][j] = a;
            }
        }

        // Channels 0..2: center copy, zeroed at col 0 / 255.
        nt_store4(ob + (size_t)i * HW,
                  (cb != 0) ? cv[0] : 0.f,
                  cv[1],
                  cv[2],
                  (cb + 3 != WW - 1) ? cv[3] : 0.f);
    }

    // Zero accumulators for border columns so all y channels are 0 there.
    #pragma unroll
    for (int j = 0; j < 4; ++j) {
        const int col = cb + j;
        if (col == 0 || col == WW - 1) {
            #pragma unroll
            for (int m = 0; m < 5; ++m) tacc[m][j] = 0.f;
        }
    }

    // y[o] = sum_m t[m] * wlT[o,m]; 64 NT dwordx4 stores.
    const float* wlT = ws + 128;
    float* yb = ob + (size_t)3 * HW;
    #pragma unroll
    for (int o = 0; o < 64; ++o) {
        const float* wo = wlT + o * 5;  // wave-uniform, contiguous 5 floats
        const float w0 = wo[0], w1 = wo[1], w2 = wo[2], w3 = wo[3], w4 = wo[4];
        float y0, y1, y2, y3;
        y0 = fmaf(tacc[4][0], w4, fmaf(tacc[3][0], w3, fmaf(tacc[2][0], w2, fmaf(tacc[1][0], w1, tacc[0][0] * w0))));
        y1 = fmaf(tacc[4][1], w4, fmaf(tacc[3][1], w3, fmaf(tacc[2][1], w2, fmaf(tacc[1][1], w1, tacc[0][1] * w0))));
        y2 = fmaf(tacc[4][2], w4, fmaf(tacc[3][2], w3, fmaf(tacc[2][2], w2, fmaf(tacc[1][2], w1, tacc[0][2] * w0))));
        y3 = fmaf(tacc[4][3], w4, fmaf(tacc[3][3], w3, fmaf(tacc[2][3], w2, fmaf(tacc[1][3], w1, tacc[0][3] * w0))));
        nt_store4(yb + (size_t)o * HW, y0, y1, y2, y3);
    }
}

extern "C" void kernel_launch(void* const* d_in, const int* in_sizes, int n_in,
                              void* d_out, int out_size, void* d_ws, size_t ws_size,
                              hipStream_t stream) {
    const float* x  = (const float*)d_in[0];
    const float* w  = (const float*)d_in[1];
    const float* wl = (const float*)d_in[2];
    float* out = (float*)d_out;
    float* ws  = (float*)d_ws;

    prep_kernel<<<1, 512, 0, stream>>>(w, wl, ws);
    lbp_kernel<<<32 * 64, 256, 0, stream>>>(x, ws, out);
}